// Round 10
// baseline (166.854 us; speedup 1.0000x reference)
//
#include <hip/hip_runtime.h>
#include <math.h>

#define HOP       128
#define NBINS     257
#define NFRAMES   4000
#define NB        16
#define OUT_LEN   512383          // (4000-1)*128 + 512 - 1
#define CPR       19              // chunks per range (per wave)
#define RPB       211             // ranges per batch = ceil(4003/19)
#define NCHUNK    4003            // output chunks of 128 (last has 127 samples)
#define NPAIRS    11              // frame-pairs per wave = (CPR+3)/2, exact
#define PBF4      320             // per-wave LDS scratch (float4) per buffer

__device__ __forceinline__ float2 cmul(float2 a, float2 b) {
    return make_float2(a.x*b.x - a.y*b.y, a.x*b.y + a.y*b.x);
}

// Opaque lane value: volatile asm breaks loop-invariance so per-stage trig
// recomputation CANNOT be LICM-hoisted back into persistent registers.
// (r5 lesson: plain remat of loop-invariant trig gets hoisted, demand stays
// high, and a tight launch_bounds cap then spills to scratch.)
__device__ __forceinline__ int opaque_i(int v) {
    asm volatile("" : "+v"(v));
    return v;
}

// Inverse-sign DFT4: y[t] = sum_j x[j] * i^(j*t)
__device__ __forceinline__ void dft4(const float2* x, float2* y) {
    const float s0r=x[0].x+x[2].x, s0i=x[0].y+x[2].y;
    const float d0r=x[0].x-x[2].x, d0i=x[0].y-x[2].y;
    const float s1r=x[1].x+x[3].x, s1i=x[1].y+x[3].y;
    const float d1r=x[1].x-x[3].x, d1i=x[1].y-x[3].y;
    y[0]=make_float2(s0r+s1r, s0i+s1i);
    y[2]=make_float2(s0r-s1r, s0i-s1i);
    y[1]=make_float2(d0r-d1i, d0i+d1r);   // d0 + i*d1
    y[3]=make_float2(d0r+d1i, d0i-d1r);   // d0 - i*d1
}

// Real-packed iSTFT, 2-frame-paired packed 256-pt inverse FFTs (.xy/.zw of
// float4 LDS slots, b128 transposes), shuffle-mirror, register OLA, no barriers.
//
// REGIME MODEL (r3-r9, twice-validated): LATENCY-bound, low util everywhere
// (VALU ~31%, LDS pipe ~28%, issue ~17%).  Wall per frame-pair per CU is a
// decreasing function of resident-wave density:
//   7.6 waves/CU -> 1224 cy (r8) | 11.4 -> 1054 (r6) | 11.94 -> 1044 (r9)
// Density is capped by the VGPR band: waves/EU = floor(256/VGPR).
// Dead levers (measured): ILP-2 (r7 +200cy/pair), reg-cap below demand
// (r1/r2/r5 spill), low-wave work reduction (r8).
//
// THIS ROUND (r10): enter the 4-waves/EU band.  Demand 72 - 8 = 64: the 8
// persistent trig VGPRs (ctw0,w1,b1,q1) become per-stage transients seeded
// by opaque_i(l) so LICM can't re-hoist them.  Cost ~+4% VALU (+4 sincos,
// +2 cmul per pair).  launch_bounds(256,4) = cap 64.
// Grid CPR=19 risk-balanced: 3376 waves / 844 blocks, 22 frames = 11 pairs
// exact.  Success (16 w/CU cap): single fill @13.2 waves/CU.  Failure
// (12 w/CU): 844/768 = 1.10 fills, bounded penalty (r4's was 1.96).
// FALSIFIER: WRITE_SIZE > 37 MB = spill -> r9 (CPR=21, (256,3)) is keeper.
__global__ __launch_bounds__(256, 4)
void istft_pk4_kernel(const float* __restrict__ re,
                      const float* __restrict__ im,
                      float* __restrict__ out)
{
    __shared__ float4 bufA[4][PBF4];   // 4 waves * 320 * 16 B = 20480 B
    __shared__ float4 bufB[4][PBF4];   // total 40960 B / block
    // LDS at 4 blocks/CU = 163840 B = exactly the 160 KiB/CU -- matches the
    // 16-waves/CU register cap, not binding beyond it.

    const int tid = threadIdx.x;
    const int wv  = tid >> 6;
    const int l   = tid & 63;
    float4* PA = bufA[wv];
    float4* PBp = bufB[wv];

    const int rid = blockIdx.x * 4 + wv;     // 0..3375 exact
    const int b   = rid / RPB;
    const int rr  = rid - b * RPB;
    const int c0  = rr * CPR;
    const int fend = min(c0 + CPR - 1, NCHUNK - 1);

    const float* __restrict__ reb = re + (size_t)b * NFRAMES * NBINS;
    const float* __restrict__ imb = im + (size_t)b * NFRAMES * NBINS;
    float* __restrict__ outb = out + (size_t)b * OUT_LEN;

    const float TWO_PI = 6.2831853071795864f;
    const float RQ = 0.70710678118654752f;

    // ---- persistent per-lane constants: ONLY the window weights (4 regs).
    //      All FFT twiddles are per-stage transients (see opaque_i note). ----
    const float S2 = 1.3020833333e-3f;    // 2 * 0.5/768
    float wwx0, wwx1, wwy0, wwy1;
    {
        const float S = 6.5104166667e-4f;   // 0.5/768
        float sx, cx; __sincosf(TWO_PI * (float)(2*l) * (1.0f/512.0f), &sx, &cx);
        wwx0 = S*(1.0f-cx); wwx1 = S*(1.0f+sx);
        float sy, cy; __sincosf(TWO_PI * (float)(2*l+1) * (1.0f/512.0f), &sy, &cy);
        wwy0 = S*(1.0f-cy); wwy1 = S*(1.0f+sy);
    }
    // Transpose layouts (float4 index; <=2-way within 16-lane phases).
    const int a1w = l;                                        // + 64*t0
    const int a1r = (l & 15) + 64 * (l >> 4);                 // + 16*q
    const int a2w = (l & 15) + 20 * (l >> 4);                 // + 80*t1
    const int a2r = (l & 3) + 20 * ((l >> 2) & 3) + 80 * (l >> 4);   // + 4*r
    const int a3w = ((l >> 2) & 3) + 4 * (l >> 4) + 20 * (l & 3);    // + 80*t2
    const int a3r = (l & 3) + 4 * ((l >> 2) & 3) + 80 * (l >> 4);    // + 20*k0

    float accx[4], accy[4];
    #pragma unroll
    for (int o = 0; o < 4; ++o) { accx[o] = 0.0f; accy[o] = 0.0f; }

    // Raw prefetch registers for the next PAIR of frames (k-side only;
    // mirrors reconstructed by shuffle at consumption).
    float dra[4], dia[4], drb[4], dib[4];
    float nyra, nyia, nyrb, nyib;

    auto issue_loads = [&](int fq) {           // frames fq (a) and fq+1 (b)
        const int fca = min(max(fq,     0), NFRAMES - 1);
        const int fcb = min(max(fq + 1, 0), NFRAMES - 1);
        const float* __restrict__ rba = reb + (size_t)fca * NBINS;
        const float* __restrict__ iba = imb + (size_t)fca * NBINS;
        const float* __restrict__ rbb = reb + (size_t)fcb * NBINS;
        const float* __restrict__ ibb = imb + (size_t)fcb * NBINS;
        #pragma unroll
        for (int j = 0; j < 4; ++j) {
            const int k = l + 64*j;
            dra[j] = rba[k]; dia[j] = iba[k];
            drb[j] = rbb[k]; dib[j] = ibb[k];
        }
        nyra = rba[256]; nyia = iba[256];      // Nyquist bin (uniform line)
        nyrb = rbb[256]; nyib = ibb[256];
    };

    // Stage-1 math for one frame: shuffle-mirror + pack + dft4 + w-twiddles.
    auto s1frame = [&](const float* dr_, const float* di_, float nyr, float nyi,
                       int revl, float2 ctw0, float2 w1, float2 w2t, float2 w3t,
                       float2* A) {
        // Reconstruct Y[256-k]: lane-reversal shuffle of the k-side loads.
        float mr_[4], mi_[4];
        #pragma unroll
        for (int j = 0; j < 4; ++j) {
            float vr = __shfl(dr_[3-j], revl, 64);
            float vi = __shfl(di_[3-j], revl, 64);
            if (j == 0) {
                if (l == 0) { vr = nyr; vi = nyi; }
            } else {
                if (l == 0) { vr = dr_[4-j]; vi = di_[4-j]; }
            }
            mr_[j] = vr; mi_[j] = vi;
        }
        float2 Cv[4];
        float cc = ctw0.x, ss = ctw0.y;   // walking twiddle, pi/4 per j-step
        #pragma unroll
        for (int j = 0; j < 4; ++j) {
            float ydr = dr_[j], ydi = di_[j], ymr = mr_[j], ymi = mi_[j];
            if (j == 0) {                       // k==0: Im of DC & Nyquist ignored
                const bool z = (l == 0);
                ydi = z ? 0.0f : ydi;
                ymi = z ? 0.0f : ymi;
            }
            const float er  = ydr + ymr, ei  = ydi - ymi;
            const float fr2 = ydr - ymr, fi2 = ydi + ymi;
            const float gr = cc*fr2 - ss*fi2;
            const float gi = cc*fi2 + ss*fr2;
            Cv[j] = make_float2(er - gi, ei + gr);
            const float cn = (cc - ss) * RQ, sn = (ss + cc) * RQ;  // rotate pi/4
            cc = cn; ss = sn;
        }
        dft4(Cv, A);
        A[1] = cmul(A[1], w1); A[2] = cmul(A[2], w2t); A[3] = cmul(A[3], w3t);
    };

    auto stage1 = [&](float4* __restrict__ P) {
        // Per-call trig from opaque lane (not hoistable -> not persistent).
        const int lo = opaque_i(l);
        float2 ctw0, w1;
        { float s, c; __sincosf(TWO_PI * (float)lo * (1.0f/512.0f), &s, &c);
          ctw0 = make_float2(c, s); }
        { float s, c; __sincosf(TWO_PI * (float)lo * (1.0f/256.0f), &s, &c);
          w1 = make_float2(c, s); }
        const float2 w2t = cmul(w1, w1);
        const float2 w3t = cmul(w2t, w1);
        const int revl = (64 - lo) & 63;
        float2 Aa[4], Ab[4];
        s1frame(dra, dia, nyra, nyia, revl, ctw0, w1, w2t, w3t, Aa);
        s1frame(drb, dib, nyrb, nyib, revl, ctw0, w1, w2t, w3t, Ab);
        #pragma unroll
        for (int j = 0; j < 4; ++j)
            P[a1w + 64*j] = make_float4(Aa[j].x, Aa[j].y, Ab[j].x, Ab[j].y);
    };

    auto stages234 = [&](float4* __restrict__ P, int fa) {
        const int lo = opaque_i(l);
        float2 Ga[4], Gb[4], Aa[4], Ab[4];
        // ---- stage 2 ----
        #pragma unroll
        for (int t = 0; t < 4; ++t) {
            const float4 g = P[a1r + 16*t];
            Ga[t] = make_float2(g.x, g.y); Gb[t] = make_float2(g.z, g.w);
        }
        dft4(Ga, Aa); dft4(Gb, Ab);
        {
            float2 b1;   // per-call trig (not hoistable)
            { float s, c; __sincosf(TWO_PI * (float)(lo & 15) * (1.0f/64.0f), &s, &c);
              b1 = make_float2(c, s); }
            const float2 b2t = cmul(b1, b1);
            const float2 b3t = cmul(b2t, b1);
            Aa[1]=cmul(Aa[1],b1); Aa[2]=cmul(Aa[2],b2t); Aa[3]=cmul(Aa[3],b3t);
            Ab[1]=cmul(Ab[1],b1); Ab[2]=cmul(Ab[2],b2t); Ab[3]=cmul(Ab[3],b3t);
        }
        #pragma unroll
        for (int t = 0; t < 4; ++t)
            P[a2w + 80*t] = make_float4(Aa[t].x, Aa[t].y, Ab[t].x, Ab[t].y);
        // ---- stage 3 ----
        #pragma unroll
        for (int t = 0; t < 4; ++t) {
            const float4 g = P[a2r + 4*t];
            Ga[t] = make_float2(g.x, g.y); Gb[t] = make_float2(g.z, g.w);
        }
        dft4(Ga, Aa); dft4(Gb, Ab);
        {
            float2 q1;   // per-call trig (not hoistable)
            { float s, c; __sincosf(TWO_PI * (float)(lo & 3) * (1.0f/16.0f), &s, &c);
              q1 = make_float2(c, s); }
            const float2 q2t = cmul(q1, q1);
            const float2 q3t = cmul(q2t, q1);
            Aa[1]=cmul(Aa[1],q1); Aa[2]=cmul(Aa[2],q2t); Aa[3]=cmul(Aa[3],q3t);
            Ab[1]=cmul(Ab[1],q1); Ab[2]=cmul(Ab[2],q2t); Ab[3]=cmul(Ab[3],q3t);
        }
        #pragma unroll
        for (int t = 0; t < 4; ++t)
            P[a3w + 80*t] = make_float4(Aa[t].x, Aa[t].y, Ab[t].x, Ab[t].y);
        // ---- stage 4 ----
        #pragma unroll
        for (int t = 0; t < 4; ++t) {
            const float4 g = P[a3r + 20*t];
            Ga[t] = make_float2(g.x, g.y); Gb[t] = make_float2(g.z, g.w);
        }
        dft4(Ga, Aa); dft4(Gb, Ab);
        // ---- OLA: frame fa first (chunk fa must NOT see frame fb), then fb ----
        const int fb = fa + 1;
        if (fa >= 0 && fa < NFRAMES) {          // wave-uniform gate
            accx[0] = fmaf(Aa[0].x, wwx0, accx[0]);
            accx[1] = fmaf(Aa[1].x, wwx1, accx[1]);
            accx[2] = fmaf(Aa[2].x, S2, fmaf(-Aa[2].x, wwx0, accx[2]));
            accx[3] = fmaf(Aa[3].x, S2, fmaf(-Aa[3].x, wwx1, accx[3]));
            accy[0] = fmaf(Aa[0].y, wwy0, accy[0]);
            accy[1] = fmaf(Aa[1].y, wwy1, accy[1]);
            accy[2] = fmaf(Aa[2].y, S2, fmaf(-Aa[2].y, wwy0, accy[2]));
            accy[3] = fmaf(Aa[3].y, S2, fmaf(-Aa[3].y, wwy1, accy[3]));
        }
        if (fa >= c0 && fa <= fend) {           // emit chunk fa (complete now)
            const int s0 = fa * HOP + 2*l;      // max 512382 < OUT_LEN
            outb[s0] = accx[0];
            const int s1 = s0 + 1;
            if (s1 < OUT_LEN) outb[s1] = accy[0];
        }
        #pragma unroll
        for (int o = 0; o < 3; ++o) { accx[o] = accx[o+1]; accy[o] = accy[o+1]; }
        accx[3] = 0.0f; accy[3] = 0.0f;
        if (fb >= 0 && fb < NFRAMES) {
            accx[0] = fmaf(Ab[0].x, wwx0, accx[0]);
            accx[1] = fmaf(Ab[1].x, wwx1, accx[1]);
            accx[2] = fmaf(Ab[2].x, S2, fmaf(-Ab[2].x, wwx0, accx[2]));
            accx[3] = fmaf(Ab[3].x, S2, fmaf(-Ab[3].x, wwx1, accx[3]));
            accy[0] = fmaf(Ab[0].y, wwy0, accy[0]);
            accy[1] = fmaf(Ab[1].y, wwy1, accy[1]);
            accy[2] = fmaf(Ab[2].y, S2, fmaf(-Ab[2].y, wwy0, accy[2]));
            accy[3] = fmaf(Ab[3].y, S2, fmaf(-Ab[3].y, wwy1, accy[3]));
        }
        if (fb >= c0 && fb <= fend) {
            const int s0 = fb * HOP + 2*l;
            outb[s0] = accx[0];
            const int s1 = s0 + 1;
            if (s1 < OUT_LEN) outb[s1] = accy[0];
        }
        #pragma unroll
        for (int o = 0; o < 3; ++o) { accx[o] = accx[o+1]; accy[o] = accy[o+1]; }
        accx[3] = 0.0f; accy[3] = 0.0f;
    };

    // ---- software-pipelined pair loop: frames c0-3 .. c0+CPR-1 (22 = 11
    //      pairs exactly; acc for chunk c0 complete at f=c0; out-of-range
    //      frames load-clamped + acc/emit-gated) ----
    const int base = c0 - 3;
    issue_loads(base);
    stage1(PA);
    float4* cur = PA;
    float4* nxt = PBp;
    #pragma unroll 1
    for (int p = 0; p < NPAIRS; ++p) {
        if (p + 1 < NPAIRS) issue_loads(base + 2*(p+1)); // fly during stages234
        stages234(cur, base + 2*p);
        if (p + 1 < NPAIRS) stage1(nxt);                 // consumes p+1 loads
        float4* t = cur; cur = nxt; nxt = t;
    }
}

extern "C" void kernel_launch(void* const* d_in, const int* in_sizes, int n_in,
                              void* d_out, int out_size, void* d_ws, size_t ws_size,
                              hipStream_t stream) {
    (void)in_sizes; (void)n_in; (void)d_ws; (void)ws_size; (void)out_size;
    const float* re = (const float*)d_in[0];
    const float* im = (const float*)d_in[1];
    float* out = (float*)d_out;

    // 16 batches x 211 ranges = 3376 waves; 4 waves per 256-thread block.
    // 844 blocks: at the 16-waves/CU cap (VGPR<=64) this is a single
    // co-resident fill at 13.2 waves/CU; at the 12-waves/CU fallback it is
    // a mild 1.10-fill (bounded regression).
    const int nblocks = (NB * RPB) / 4;   // 844
    istft_pk4_kernel<<<dim3(nblocks), dim3(256), 0, stream>>>(re, im, out);
}

// Round 11
// 163.850 us; speedup vs baseline: 1.0183x; 1.0183x over previous
//
#include <hip/hip_runtime.h>
#include <math.h>

#define HOP       128
#define NBINS     257
#define NFRAMES   4000
#define NB        16
#define OUT_LEN   512383          // (4000-1)*128 + 512 - 1
#define CPR       21              // chunks per range (per wave)
#define RPB       191             // ranges per batch = ceil(4003/21)
#define NCHUNK    4003            // output chunks of 128 (last has 127 samples)
#define NPAIRS    12              // frame-pairs per wave = (CPR+3)/2, exact
#define PBF4      320             // per-wave LDS scratch (float4) per buffer

__device__ __forceinline__ float2 cmul(float2 a, float2 b) {
    return make_float2(a.x*b.x - a.y*b.y, a.x*b.y + a.y*b.x);
}

// Inverse-sign DFT4: y[t] = sum_j x[j] * i^(j*t)
__device__ __forceinline__ void dft4(const float2* x, float2* y) {
    const float s0r=x[0].x+x[2].x, s0i=x[0].y+x[2].y;
    const float d0r=x[0].x-x[2].x, d0i=x[0].y-x[2].y;
    const float s1r=x[1].x+x[3].x, s1i=x[1].y+x[3].y;
    const float d1r=x[1].x-x[3].x, d1i=x[1].y-x[3].y;
    y[0]=make_float2(s0r+s1r, s0i+s1i);
    y[2]=make_float2(s0r-s1r, s0i-s1i);
    y[1]=make_float2(d0r-d1i, d0i+d1r);   // d0 + i*d1
    y[3]=make_float2(d0r+d1i, d0i-d1r);   // d0 - i*d1
}

// Real-packed iSTFT, 2-frame-paired packed 256-pt inverse FFTs (.xy/.zw of
// float4 LDS slots, b128 transposes), shuffle-mirror, register OLA, no barriers.
//
// ===== FINAL LEDGER (r0-r10), all measured on MI355X =====
// r0  82.0us  baseline 1-frame (68 VGPR)
// r1 293us    (256,8) cap32: spill catastrophe       [dead: reg-cap < demand]
// r2 160us    (256,4) cap64 on pk4: spill            [dead]
// r3  72.4us  pk4 pairing + (256,2)                  [WIN: per-wave ILP]
// r4  76us    CPR=16: 2 ragged fills                 [dead: ragged fills]
// r5  81us    trim-to-85: LICM re-hoist -> spill     [dead: remat w/o opaque]
// r6  64.9us  shuffle-mirror, 72 VGPR, zero spill    [WIN: -16 regs, -50% loads]
// r7  74us    pk8 ILP-2                              [dead: +200cy/pair]
// r8  70us    CPR=33 @ 7.6 waves/CU                  [dead: density starves]
// r9  62.3us  CPR=21, 12 pairs exact, max density    [WIN -- THIS KERNEL]
// r10 70.3us  VGPR 56 via opaque-remat: occupancy UNCHANGED (~24% for VGPR
//             56/72/88 alike) + trig VALU +26%       [dead: density not
//             VGPR-limited in 56-72 band; trans-pipe remat too costly]
//
// REGIME (final): latency-bound on 3 dependent LDS round-trips per pair;
// achieved density pinned ~2 waves/EU regardless of VGPR band; VALU ~31%,
// LDS pipe ~30%, issue ~17% -- no pipe near saturation, all measured levers
// (TLP, ILP, reg-bands, work-min, conflicts<=2-way-by-construction) exhausted.
// Remaining unexplored: radix-8 restructure (3->2 round-trips, ~20% modeled,
// high rewrite risk) -- declined.
__global__ __launch_bounds__(256, 3)
void istft_pk4_kernel(const float* __restrict__ re,
                      const float* __restrict__ im,
                      float* __restrict__ out)
{
    __shared__ float4 bufA[4][PBF4];   // 4 waves * 320 * 16 B = 20480 B
    __shared__ float4 bufB[4][PBF4];   // total 40960 B / block

    const int tid = threadIdx.x;
    const int wv  = tid >> 6;
    const int l   = tid & 63;
    float4* PA = bufA[wv];
    float4* PBp = bufB[wv];

    const int rid = blockIdx.x * 4 + wv;     // 0..3055 exact
    const int b   = rid / RPB;
    const int rr  = rid - b * RPB;
    const int c0  = rr * CPR;
    const int fend = min(c0 + CPR - 1, NCHUNK - 1);

    const float* __restrict__ reb = re + (size_t)b * NFRAMES * NBINS;
    const float* __restrict__ imb = im + (size_t)b * NFRAMES * NBINS;
    float* __restrict__ outb = out + (size_t)b * OUT_LEN;

    // ---- frame-invariant per-lane constants (persistent set minimal:
    //      ctw0, w1, b1, q1, ww*4; squares/cubes remat per use) ----
    const float TWO_PI = 6.2831853071795864f;
    const float RQ = 0.70710678118654752f;
    float2 ctw0;
    { float s, c; __sincosf(TWO_PI * (float)l * (1.0f/512.0f), &s, &c);
      ctw0 = make_float2(c, s); }
    float2 w1;
    { float s, c; __sincosf(TWO_PI * (float)l * (1.0f/256.0f), &s, &c);
      w1 = make_float2(c, s); }
    float2 b1;
    { float s, c; __sincosf(TWO_PI * (float)(l & 15) * (1.0f/64.0f), &s, &c);
      b1 = make_float2(c, s); }
    float2 q1;
    { float s, c; __sincosf(TWO_PI * (float)(l & 3) * (1.0f/16.0f), &s, &c);
      q1 = make_float2(c, s); }
    // Window weights for samples 2l+128o (x) / 2l+1+128o (y); Hann identity
    // ww[2]=2S-ww[0], ww[3]=2S-ww[1] keeps only o=0,1 persistent.
    const float S2 = 1.3020833333e-3f;    // 2 * 0.5/768
    float wwx0, wwx1, wwy0, wwy1;
    {
        const float S = 6.5104166667e-4f;   // 0.5/768
        float sx, cx; __sincosf(TWO_PI * (float)(2*l) * (1.0f/512.0f), &sx, &cx);
        wwx0 = S*(1.0f-cx); wwx1 = S*(1.0f+sx);
        float sy, cy; __sincosf(TWO_PI * (float)(2*l+1) * (1.0f/512.0f), &sy, &cy);
        wwy0 = S*(1.0f-cy); wwy1 = S*(1.0f+sy);
    }
    // Transpose layouts (float4 index).  Bank analysis (8-lane phase groups,
    // idx mod 8 distinct required): a1w/a1r/a2w/a2r/a3r conflict-free,
    // a3w 2-way (free per m136).  The ~3.8M SQ_LDS_BANK_CONFLICT counter is
    // counted-but-pipelined 2-way + bpermute crossbar -- not actionable.
    const int a1w = l;                                        // + 64*t0
    const int a1r = (l & 15) + 64 * (l >> 4);                 // + 16*q
    const int a2w = (l & 15) + 20 * (l >> 4);                 // + 80*t1
    const int a2r = (l & 3) + 20 * ((l >> 2) & 3) + 80 * (l >> 4);   // + 4*r
    const int a3w = ((l >> 2) & 3) + 4 * (l >> 4) + 20 * (l & 3);    // + 80*t2
    const int a3r = (l & 3) + 4 * ((l >> 2) & 3) + 80 * (l >> 4);    // + 20*k0
    const int revl = (64 - l) & 63;                           // mirror src lane

    float accx[4], accy[4];
    #pragma unroll
    for (int o = 0; o < 4; ++o) { accx[o] = 0.0f; accy[o] = 0.0f; }

    // Raw prefetch registers for the next PAIR of frames (k-side only;
    // mirrors reconstructed by shuffle at consumption).
    float dra[4], dia[4], drb[4], dib[4];
    float nyra, nyia, nyrb, nyib;

    auto issue_loads = [&](int fq) {           // frames fq (a) and fq+1 (b)
        const int fca = min(max(fq,     0), NFRAMES - 1);
        const int fcb = min(max(fq + 1, 0), NFRAMES - 1);
        const float* __restrict__ rba = reb + (size_t)fca * NBINS;
        const float* __restrict__ iba = imb + (size_t)fca * NBINS;
        const float* __restrict__ rbb = reb + (size_t)fcb * NBINS;
        const float* __restrict__ ibb = imb + (size_t)fcb * NBINS;
        #pragma unroll
        for (int j = 0; j < 4; ++j) {
            const int k = l + 64*j;
            dra[j] = rba[k]; dia[j] = iba[k];
            drb[j] = rbb[k]; dib[j] = ibb[k];
        }
        nyra = rba[256]; nyia = iba[256];      // Nyquist bin (uniform line)
        nyrb = rbb[256]; nyib = ibb[256];
    };

    // Stage-1 math for one frame: shuffle-mirror + pack + dft4 + w-twiddles.
    auto s1frame = [&](const float* dr_, const float* di_, float nyr, float nyi,
                       float2 w2t, float2 w3t, float2* A) {
        // Reconstruct Y[256-k]: lane-reversal shuffle of the k-side loads.
        float mr_[4], mi_[4];
        #pragma unroll
        for (int j = 0; j < 4; ++j) {
            float vr = __shfl(dr_[3-j], revl, 64);
            float vi = __shfl(di_[3-j], revl, 64);
            if (j == 0) {
                if (l == 0) { vr = nyr; vi = nyi; }
            } else {
                if (l == 0) { vr = dr_[4-j]; vi = di_[4-j]; }
            }
            mr_[j] = vr; mi_[j] = vi;
        }
        float2 Cv[4];
        float cc = ctw0.x, ss = ctw0.y;   // walking twiddle, pi/4 per j-step
        #pragma unroll
        for (int j = 0; j < 4; ++j) {
            float ydr = dr_[j], ydi = di_[j], ymr = mr_[j], ymi = mi_[j];
            if (j == 0) {                       // k==0: Im of DC & Nyquist ignored
                const bool z = (l == 0);
                ydi = z ? 0.0f : ydi;
                ymi = z ? 0.0f : ymi;
            }
            const float er  = ydr + ymr, ei  = ydi - ymi;
            const float fr2 = ydr - ymr, fi2 = ydi + ymi;
            const float gr = cc*fr2 - ss*fi2;
            const float gi = cc*fi2 + ss*fr2;
            Cv[j] = make_float2(er - gi, ei + gr);
            const float cn = (cc - ss) * RQ, sn = (ss + cc) * RQ;  // rotate pi/4
            cc = cn; ss = sn;
        }
        dft4(Cv, A);
        A[1] = cmul(A[1], w1); A[2] = cmul(A[2], w2t); A[3] = cmul(A[3], w3t);
    };

    auto stage1 = [&](float4* __restrict__ P) {
        const float2 w2t = cmul(w1, w1);       // transient remat (reg slack)
        const float2 w3t = cmul(w2t, w1);
        float2 Aa[4], Ab[4];
        s1frame(dra, dia, nyra, nyia, w2t, w3t, Aa);
        s1frame(drb, dib, nyrb, nyib, w2t, w3t, Ab);
        #pragma unroll
        for (int j = 0; j < 4; ++j)
            P[a1w + 64*j] = make_float4(Aa[j].x, Aa[j].y, Ab[j].x, Ab[j].y);
    };

    auto stages234 = [&](float4* __restrict__ P, int fa) {
        float2 Ga[4], Gb[4], Aa[4], Ab[4];
        // ---- stage 2 ----
        #pragma unroll
        for (int t = 0; t < 4; ++t) {
            const float4 g = P[a1r + 16*t];
            Ga[t] = make_float2(g.x, g.y); Gb[t] = make_float2(g.z, g.w);
        }
        dft4(Ga, Aa); dft4(Gb, Ab);
        {
            const float2 b2t = cmul(b1, b1);   // transient remat
            const float2 b3t = cmul(b2t, b1);
            Aa[1]=cmul(Aa[1],b1); Aa[2]=cmul(Aa[2],b2t); Aa[3]=cmul(Aa[3],b3t);
            Ab[1]=cmul(Ab[1],b1); Ab[2]=cmul(Ab[2],b2t); Ab[3]=cmul(Ab[3],b3t);
        }
        #pragma unroll
        for (int t = 0; t < 4; ++t)
            P[a2w + 80*t] = make_float4(Aa[t].x, Aa[t].y, Ab[t].x, Ab[t].y);
        // ---- stage 3 ----
        #pragma unroll
        for (int t = 0; t < 4; ++t) {
            const float4 g = P[a2r + 4*t];
            Ga[t] = make_float2(g.x, g.y); Gb[t] = make_float2(g.z, g.w);
        }
        dft4(Ga, Aa); dft4(Gb, Ab);
        {
            const float2 q2t = cmul(q1, q1);   // transient remat
            const float2 q3t = cmul(q2t, q1);
            Aa[1]=cmul(Aa[1],q1); Aa[2]=cmul(Aa[2],q2t); Aa[3]=cmul(Aa[3],q3t);
            Ab[1]=cmul(Ab[1],q1); Ab[2]=cmul(Ab[2],q2t); Ab[3]=cmul(Ab[3],q3t);
        }
        #pragma unroll
        for (int t = 0; t < 4; ++t)
            P[a3w + 80*t] = make_float4(Aa[t].x, Aa[t].y, Ab[t].x, Ab[t].y);
        // ---- stage 4 ----
        #pragma unroll
        for (int t = 0; t < 4; ++t) {
            const float4 g = P[a3r + 20*t];
            Ga[t] = make_float2(g.x, g.y); Gb[t] = make_float2(g.z, g.w);
        }
        dft4(Ga, Aa); dft4(Gb, Ab);
        // ---- OLA: frame fa first (chunk fa must NOT see frame fb), then fb ----
        const int fb = fa + 1;
        if (fa >= 0 && fa < NFRAMES) {          // wave-uniform gate
            accx[0] = fmaf(Aa[0].x, wwx0, accx[0]);
            accx[1] = fmaf(Aa[1].x, wwx1, accx[1]);
            accx[2] = fmaf(Aa[2].x, S2, fmaf(-Aa[2].x, wwx0, accx[2]));
            accx[3] = fmaf(Aa[3].x, S2, fmaf(-Aa[3].x, wwx1, accx[3]));
            accy[0] = fmaf(Aa[0].y, wwy0, accy[0]);
            accy[1] = fmaf(Aa[1].y, wwy1, accy[1]);
            accy[2] = fmaf(Aa[2].y, S2, fmaf(-Aa[2].y, wwy0, accy[2]));
            accy[3] = fmaf(Aa[3].y, S2, fmaf(-Aa[3].y, wwy1, accy[3]));
        }
        if (fa >= c0 && fa <= fend) {           // emit chunk fa (complete now)
            const int s0 = fa * HOP + 2*l;      // max 512382 < OUT_LEN
            outb[s0] = accx[0];
            const int s1 = s0 + 1;
            if (s1 < OUT_LEN) outb[s1] = accy[0];
        }
        #pragma unroll
        for (int o = 0; o < 3; ++o) { accx[o] = accx[o+1]; accy[o] = accy[o+1]; }
        accx[3] = 0.0f; accy[3] = 0.0f;
        if (fb >= 0 && fb < NFRAMES) {
            accx[0] = fmaf(Ab[0].x, wwx0, accx[0]);
            accx[1] = fmaf(Ab[1].x, wwx1, accx[1]);
            accx[2] = fmaf(Ab[2].x, S2, fmaf(-Ab[2].x, wwx0, accx[2]));
            accx[3] = fmaf(Ab[3].x, S2, fmaf(-Ab[3].x, wwx1, accx[3]));
            accy[0] = fmaf(Ab[0].y, wwy0, accy[0]);
            accy[1] = fmaf(Ab[1].y, wwy1, accy[1]);
            accy[2] = fmaf(Ab[2].y, S2, fmaf(-Ab[2].y, wwy0, accy[2]));
            accy[3] = fmaf(Ab[3].y, S2, fmaf(-Ab[3].y, wwy1, accy[3]));
        }
        if (fb >= c0 && fb <= fend) {
            const int s0 = fb * HOP + 2*l;
            outb[s0] = accx[0];
            const int s1 = s0 + 1;
            if (s1 < OUT_LEN) outb[s1] = accy[0];
        }
        #pragma unroll
        for (int o = 0; o < 3; ++o) { accx[o] = accx[o+1]; accy[o] = accy[o+1]; }
        accx[3] = 0.0f; accy[3] = 0.0f;
    };

    // ---- software-pipelined pair loop: frames c0-3 .. c0+CPR-1 (24 = 12
    //      pairs exactly; acc for chunk c0 complete at f=c0; out-of-range
    //      frames load-clamped + acc/emit-gated) ----
    const int base = c0 - 3;
    issue_loads(base);
    stage1(PA);
    float4* cur = PA;
    float4* nxt = PBp;
    #pragma unroll 1
    for (int p = 0; p < NPAIRS; ++p) {
        if (p + 1 < NPAIRS) issue_loads(base + 2*(p+1)); // fly during stages234
        stages234(cur, base + 2*p);
        if (p + 1 < NPAIRS) stage1(nxt);                 // consumes p+1 loads
        float4* t = cur; cur = nxt; nxt = t;
    }
}

extern "C" void kernel_launch(void* const* d_in, const int* in_sizes, int n_in,
                              void* d_out, int out_size, void* d_ws, size_t ws_size,
                              hipStream_t stream) {
    (void)in_sizes; (void)n_in; (void)d_ws; (void)ws_size; (void)out_size;
    const float* re = (const float*)d_in[0];
    const float* im = (const float*)d_in[1];
    float* out = (float*)d_out;

    // 16 batches x 191 ranges = 3056 waves; 4 waves per 256-thread block.
    // 764 blocks ~= 3 blocks/CU exactly -> balanced single fill (measured
    // best density: 1044 cy/pair-CU, 62.3us dispatch).
    const int nblocks = (NB * RPB) / 4;   // 764
    istft_pk4_kernel<<<dim3(nblocks), dim3(256), 0, stream>>>(re, im, out);
}